// Round 11
// baseline (156.427 us; speedup 1.0000x reference)
//
#include <hip/hip_runtime.h>

// 8-level DWT + 8-level per-channel IDWT.
//  fwd03: wave-local barrier-free pyramid (unchanged from r10).
//  mid_fused: fwd 4-7 + inv 7-4 per row (unchanged).
//  inv23: inverse levels 3+2 fused (register recompute of prev2, no LDS).
//  inv01: inverse levels 1+0 fused (register recompute of prev0, no LDS).

static __constant__ float c_dec_lo[10] = {
    0.003335725285001549f, -0.012580751999015526f, -0.006241490213011705f,
    0.07757149384006515f, -0.03224486958502952f, -0.24229488706619015f,
    0.13842814590110342f, 0.7243085284385744f, 0.6038292697974729f,
    0.160102397974125f};
static __constant__ float c_dec_hi[10] = {
    -0.160102397974125f, 0.6038292697974729f, -0.7243085284385744f,
    0.13842814590110342f, 0.24229488706619015f, -0.03224486958502952f,
    -0.07757149384006515f, -0.006241490213011705f, 0.012580751999015526f,
    0.003335725285001549f};

__device__ inline float4 ldz4(const float* __restrict__ row, int j, int L) {
  if (j >= 0 && j + 3 < L) return *reinterpret_cast<const float4*>(row + j);
  float4 r;
  r.x = (j + 0 >= 0 && j + 0 < L) ? row[j + 0] : 0.f;
  r.y = (j + 1 >= 0 && j + 1 < L) ? row[j + 1] : 0.f;
  r.z = (j + 2 >= 0 && j + 2 < L) ? row[j + 2] : 0.f;
  r.w = (j + 3 >= 0 && j + 3 < L) ? row[j + 3] : 0.f;
  return r;
}

__device__ inline void load20(const float* src, int base, float* v) {
#pragma unroll
  for (int q = 0; q < 5; ++q) {
    const float4 t = *reinterpret_cast<const float4*>(src + base + 4 * q);
    v[4 * q + 0] = t.x; v[4 * q + 1] = t.y;
    v[4 * q + 2] = t.z; v[4 * q + 3] = t.w;
  }
}

__device__ inline void load20z(const float* __restrict__ src, int base, int L,
                               float* v) {
#pragma unroll
  for (int q = 0; q < 5; ++q) {
    const float4 t = ldz4(src, base + 4 * q, L);
    v[4 * q + 0] = t.x; v[4 * q + 1] = t.y;
    v[4 * q + 2] = t.z; v[4 * q + 3] = t.w;
  }
}

__device__ inline void load12(const float* src, float* v) {
#pragma unroll
  for (int q = 0; q < 3; ++q) {
    const float4 t = *reinterpret_cast<const float4*>(src + 4 * q);
    v[4 * q + 0] = t.x; v[4 * q + 1] = t.y;
    v[4 * q + 2] = t.z; v[4 * q + 3] = t.w;
  }
}

__device__ inline void fir10x2(const float* v, float* lo, float* hv) {
#pragma unroll
  for (int i = 0; i < 4; ++i) {
    float a = 0.f, h = 0.f;
#pragma unroll
    for (int k = 0; k < 10; ++k) {
      const float xx = v[2 * i + 3 + k];
      a += xx * c_dec_lo[k];
      h += xx * c_dec_hi[k];
    }
    lo[i] = a; hv[i] = h;
  }
}

__device__ inline void fir10x2_split(const float* e, const float* o,
                                     float* lo, float* hv) {
#pragma unroll
  for (int i = 0; i < 4; ++i) {
    float a = 0.f, h = 0.f;
#pragma unroll
    for (int m = 0; m < 5; ++m) {
      const float ov = o[i + 1 + m], ev = e[i + 2 + m];
      a += ov * c_dec_lo[2 * m] + ev * c_dec_lo[2 * m + 1];
      h += ov * c_dec_hi[2 * m] + ev * c_dec_hi[2 * m + 1];
    }
    lo[i] = a; hv[i] = h;
  }
}

__device__ inline void store_hi(float* hg, int A, int idx, const float* hv,
                                int es, int ee) {
  if (idx >= es && idx + 3 < ee) {
    *reinterpret_cast<float4*>(hg + A + idx) =
        make_float4(hv[0], hv[1], hv[2], hv[3]);
  } else {
#pragma unroll
    for (int i = 0; i < 4; ++i)
      if (idx + i >= es && idx + i < ee) hg[A + idx + i] = hv[i];
  }
}

__device__ inline void st4(float* dst, const float* a) {
  *reinterpret_cast<float4*>(dst) = make_float4(a[0], a[1], a[2], a[3]);
}

__device__ inline void store_pad_split(float* E, float* O, int idx,
                                       const float* lo, int vlo, int vhi) {
#pragma unroll
  for (int i = 0; i < 4; ++i) {
    const int s = idx + i;
    const float val = (s >= vlo && s < vhi) ? lo[i] : 0.f;
    if (s & 1) O[s >> 1] = val;
    else E[s >> 1] = val;
  }
}

__device__ inline void wave_sync() {
  __builtin_amdgcn_wave_barrier();
  asm volatile("s_waitcnt lgkmcnt(0)" ::: "memory");
  __builtin_amdgcn_wave_barrier();
}

// ---------------- fwd levels 0-3: wave-local pyramid (r10) ----------------
template <bool FAST>
__device__ inline void wl_level0(const float* __restrict__ xr, float* E0,
                                 float* O0, float* __restrict__ h0, int A0,
                                 int xoff, int vlo, int vhi, int eeh,
                                 int lane) {
#pragma unroll
  for (int i = 0; i < 5; ++i) {
    const int idx = 4 * lane + 256 * i;
    if (idx < 1108) {
      float v[20];
      if (FAST) load20(xr, 2 * idx + xoff, v);
      else load20z(xr, 2 * idx + xoff, 131072, v);
      float lo[4], hv[4];
      fir10x2(v, lo, hv);
      if (FAST) {
        const int j = idx >> 1;
        *reinterpret_cast<float2*>(E0 + j) = make_float2(lo[0], lo[2]);
        *reinterpret_cast<float2*>(O0 + j) = make_float2(lo[1], lo[3]);
        if (idx >= 56 && idx < 1080) st4(h0 + A0 + idx, hv);
      } else {
        store_pad_split(E0, O0, idx, lo, vlo, vhi);
        store_hi(h0, A0, idx, hv, 56, eeh);
      }
    }
  }
}

template <bool FAST>
__device__ inline void wl_levelN(const float* Ein, const float* Oin,
                                 float* Eout, float* Oout,
                                 float* __restrict__ hg, int A, int NOUT,
                                 int iters, int esHi, int eeHiF, int vlo,
                                 int vhi, int lane) {
  for (int i = 0; i < iters; ++i) {
    const int idx = 4 * lane + 256 * i;
    if (idx < NOUT) {
      float e[12], o[12];
      load12(Ein + idx, e);
      load12(Oin + idx, o);
      float lo[4], hv[4];
      fir10x2_split(e, o, lo, hv);
      if (FAST) {
        const int j = idx >> 1;
        *reinterpret_cast<float2*>(Eout + j) = make_float2(lo[0], lo[2]);
        *reinterpret_cast<float2*>(Oout + j) = make_float2(lo[1], lo[3]);
        if (idx >= esHi && idx < eeHiF) st4(hg + A + idx, hv);
      } else {
        store_pad_split(Eout, Oout, idx, lo, vlo, vhi);
        store_hi(hg, A, idx, hv, esHi, min(eeHiF, vhi));
      }
    }
  }
}

template <bool FAST>
__device__ inline void wl_level3(const float* Ein, const float* Oin,
                                 float* __restrict__ l3,
                                 float* __restrict__ h3, int T, int ne3,
                                 int lane) {
  const int idx = 4 * lane;
  if (idx >= 128) return;
  float e[12], o[12];
  load12(Ein + idx, e);
  load12(Oin + idx, o);
  float lo[4], hv[4];
  fir10x2_split(e, o, lo, hv);
  if (FAST) {
    st4(l3 + T + idx, lo);
    st4(h3 + T + idx, hv);
  } else {
    store_hi(l3, T, idx, lo, 0, ne3);
    store_hi(h3, T, idx, hv, 0, ne3);
  }
}

__global__ __launch_bounds__(256) void fwd03(
    const float* __restrict__ x, float* __restrict__ hi0,
    float* __restrict__ hi1, float* __restrict__ hi2,
    float* __restrict__ hi3, float* __restrict__ lo3) {
  const int b = blockIdx.y;
  const int widx = threadIdx.x >> 6;
  const int lane = threadIdx.x & 63;
  const int gw = blockIdx.x * 4 + widx;
  __shared__ float W[7744];
  float* E0 = W + widx * 1936;
  float* O0 = E0 + 556;
  float* E1 = O0 + 556;
  float* O1 = E1 + 276;
  float* E2 = O1 + 276;
  float* O2 = E2 + 136;
  if (gw > 64) return;
  const int T = gw * 128;
  const float* xr = x + (size_t)b * 131072;
  float* h0 = hi0 + (size_t)b * 65540;
  float* h1 = hi1 + (size_t)b * 32772;
  float* h2 = hi2 + (size_t)b * 16388;
  float* h3 = hi3 + (size_t)b * 8196;
  float* l3 = lo3 + (size_t)b * 8196;
  const int A0 = 8 * T - 56, A1 = 4 * T - 24, A2 = 2 * T - 8;
  const int xoff = 16 * T - 120;

  if (gw >= 1 && gw <= 62) {
    wl_level0<true>(xr, E0, O0, h0, A0, xoff, 0, 0, 0, lane);
    wave_sync();
    wl_levelN<true>(E0, O0, E1, O1, h1, A1, 548, 3, 24, 536, 0, 0, lane);
    wave_sync();
    wl_levelN<true>(E1, O1, E2, O2, h2, A2, 268, 2, 8, 264, 0, 0, lane);
    wave_sync();
    wl_level3<true>(E2, O2, l3, h3, T, 128, lane);
  } else {
    wl_level0<false>(xr, E0, O0, h0, A0, xoff, (A0 < 0) ? -A0 : 0,
                     min(1108, 65537 - A0), min(1080, 65537 - A0), lane);
    wave_sync();
    wl_levelN<false>(E0, O0, E1, O1, h1, A1, 548, 3, 24, 536,
                     (A1 < 0) ? -A1 : 0, min(548, 32769 - A1), lane);
    wave_sync();
    wl_levelN<false>(E1, O1, E2, O2, h2, A2, 268, 2, 8, 264,
                     (A2 < 0) ? -A2 : 0, min(268, 16385 - A2), lane);
    wave_sync();
    wl_level3<false>(E2, O2, l3, h3, T, min(128, 8193 - T), lane);
  }
}

// ---------------- even/odd-pair inverse accumulator ----------------
// acc[2e]   (even abs offset) uses odd taps  w.y/w.w at p[e+1+m]
// acc[2e+1] (odd)             uses even taps w.x/w.z at p[e+1+m]
template <int NE>
__device__ inline void accum_pairs(const float* p, const float* h,
                                   const float4* wpk, float* acc) {
#pragma unroll
  for (int i = 0; i < 2 * NE; ++i) acc[i] = 0.f;
#pragma unroll
  for (int m = 0; m < 16; ++m) {
    const float4 w = wpk[m];
#pragma unroll
    for (int e = 0; e < NE; ++e) {
      const float pv = p[e + 1 + m], hv = h[e + 1 + m];
      acc[2 * e + 0] += pv * w.y + hv * w.w;
      acc[2 * e + 1] += pv * w.x + hv * w.z;
    }
  }
}

// 8-output version used by mid tail.
__device__ inline void inv_accum(const float* p, const float* h,
                                 const float4* wpk, float* acc) {
  accum_pairs<4>(p, h, wpk, acc);
}

// ---------------- fused two inverse levels, register recompute --------------
// Thread g: 16 outputs at t0=16g of the LOWER level. Mid (upper-out) window
// pm[24] at U0=8g-8 is computed in registers from prevU/hiU windows of 28
// floats at V0=4g-12. No LDS (except filter broadcast), no barriers.
__global__ __launch_bounds__(256) void inv_fused2(
    const float* __restrict__ prevU, const float* __restrict__ hiU,
    const float* __restrict__ hiL, const float* __restrict__ filt, int lvlU,
    int lvlL, int Lu, int sU, int Lmid, int sL, int Tout, int sOut,
    float* __restrict__ out) {
  const int c = blockIdx.y;
  __shared__ float4 wp[32];  // [0:16) upper filters, [16:32) lower
  const int tid = threadIdx.x;
  if (tid < 32) {
    const int lvl = (tid < 16) ? lvlU : lvlL;
    const int m = tid & 15;
    const float* f = filt + ((size_t)c * 8 + lvl) * 64;
    wp[tid] = make_float4(f[2 * m], f[2 * m + 1], f[32 + 2 * m],
                          f[32 + 2 * m + 1]);
  }
  __syncthreads();
  const int g = blockIdx.x * 256 + tid;
  const int t0 = 16 * g;
  if (t0 >= Tout) return;
  const int U0 = 8 * g - 8;
  const int V0 = 4 * g - 12;
  const float* pu = prevU + (size_t)c * sU;
  const float* hu = hiU + (size_t)c * sU;
  const float* hl = hiL + (size_t)c * sL;

  const bool interior = (V0 >= 0) && (V0 + 27 < Lu) && (U0 >= 0) &&
                        (U0 + 23 < Lmid) && (t0 + 15 < Tout);
  float pw[28], hw[28];
  if (interior) {
#pragma unroll
    for (int q = 0; q < 7; ++q) {
      const float4 a = *reinterpret_cast<const float4*>(pu + V0 + 4 * q);
      pw[4 * q + 0] = a.x; pw[4 * q + 1] = a.y;
      pw[4 * q + 2] = a.z; pw[4 * q + 3] = a.w;
      const float4 b = *reinterpret_cast<const float4*>(hu + V0 + 4 * q);
      hw[4 * q + 0] = b.x; hw[4 * q + 1] = b.y;
      hw[4 * q + 2] = b.z; hw[4 * q + 3] = b.w;
    }
  } else {
#pragma unroll
    for (int q = 0; q < 7; ++q) {
      const float4 a = ldz4(pu, V0 + 4 * q, Lu);
      pw[4 * q + 0] = a.x; pw[4 * q + 1] = a.y;
      pw[4 * q + 2] = a.z; pw[4 * q + 3] = a.w;
      const float4 b = ldz4(hu, V0 + 4 * q, Lu);
      hw[4 * q + 0] = b.x; hw[4 * q + 1] = b.y;
      hw[4 * q + 2] = b.z; hw[4 * q + 3] = b.w;
    }
  }

  float pm[24];
  accum_pairs<12>(pw, hw, wp, pm);
  if (!interior) {
#pragma unroll
    for (int q = 0; q < 24; ++q) {
      const int j = U0 + q;
      if (j < 0 || j >= Lmid) pm[q] = 0.f;
    }
  }

  float hm[24];
  if (interior) {
#pragma unroll
    for (int q = 0; q < 6; ++q) {
      const float4 b = *reinterpret_cast<const float4*>(hl + U0 + 4 * q);
      hm[4 * q + 0] = b.x; hm[4 * q + 1] = b.y;
      hm[4 * q + 2] = b.z; hm[4 * q + 3] = b.w;
    }
  } else {
#pragma unroll
    for (int q = 0; q < 6; ++q) {
      const float4 b = ldz4(hl, U0 + 4 * q, Lmid);
      hm[4 * q + 0] = b.x; hm[4 * q + 1] = b.y;
      hm[4 * q + 2] = b.z; hm[4 * q + 3] = b.w;
    }
  }

  float acc[16];
  accum_pairs<8>(pm, hm, wp + 16, acc);

  float* orow = out + (size_t)c * sOut;
  if (interior) {
#pragma unroll
    for (int q = 0; q < 4; ++q)
      *reinterpret_cast<float4*>(orow + t0 + 4 * q) =
          make_float4(acc[4 * q], acc[4 * q + 1], acc[4 * q + 2],
                      acc[4 * q + 3]);
  } else {
#pragma unroll
    for (int i = 0; i < 16; ++i)
      if (t0 + i < Tout) orow[t0 + i] = acc[i];
  }
}

// ---------------- middle: fwd 4-7 + inv 7-4, one block per row --------------
__device__ inline void fwd_tail_level(const float* __restrict__ in,
                                      float* __restrict__ outp, int L, int D,
                                      float* __restrict__ hirow, int tid) {
  for (int d0 = 4 * tid; d0 < D; d0 += 2048) {
    const int jb = 2 * d0 - 8;
    float v[20];
    const bool interior = (jb >= 0) && (jb + 19 < L) && (d0 + 3 < D);
    if (interior) {
      load20(in, jb, v);
    } else {
#pragma unroll
      for (int q = 0; q < 20; ++q) {
        const int j = jb + q;
        v[q] = (j >= 0 && j < L) ? in[j] : 0.f;
      }
    }
    float lo[4], hv[4];
    fir10x2(v, lo, hv);
    if (interior) {
      st4(outp + d0, lo);
      st4(hirow + d0, hv);
    } else {
#pragma unroll
      for (int i = 0; i < 4; ++i)
        if (d0 + i < D) { outp[d0 + i] = lo[i]; hirow[d0 + i] = hv[i]; }
    }
  }
}

__device__ inline void inv_tail_level(const float* __restrict__ pin,
                                      float* __restrict__ pout, int L,
                                      const float* __restrict__ hirow,
                                      const float* __restrict__ filt, int c,
                                      int level, int tid, float4* wpack) {
  __syncthreads();
  if (tid < 16) {
    const float* f = filt + ((size_t)c * 8 + level) * 64;
    wpack[tid] = make_float4(f[2 * tid], f[2 * tid + 1], f[32 + 2 * tid],
                             f[32 + 2 * tid + 1]);
  }
  __syncthreads();
  const int Tout = 2 * L - 1;
  for (int t0 = 8 * tid; t0 < Tout; t0 += 4096) {
    const int U = t0 / 2 - 8;
    float p[20], h[20];
    if (U >= 0 && U + 19 < L) {
      load20(pin, U, p);
      load20(hirow, U, h);
    } else {
#pragma unroll
      for (int q = 0; q < 20; ++q) {
        const int j = U + q;
        p[q] = (j >= 0 && j < L) ? pin[j] : 0.f;
        h[q] = (j >= 0 && j < L) ? hirow[j] : 0.f;
      }
    }
    float acc[8];
    inv_accum(p, h, wpack, acc);
    if (t0 + 7 < Tout) {
      st4(pout + t0, acc);
      st4(pout + t0 + 4, acc + 4);
    } else {
#pragma unroll
      for (int i = 0; i < 8; ++i)
        if (t0 + i < Tout) pout[t0 + i] = acc[i];
    }
  }
}

__global__ __launch_bounds__(512) void mid_fused(
    const float* __restrict__ lo3, const float* __restrict__ filt,
    float* __restrict__ prev3out) {
  const int b = blockIdx.x;
  __shared__ float A[8200];
  __shared__ float Bb[4104];
  __shared__ float H4[4100];
  __shared__ float H5[2052];
  __shared__ float H6[1028];
  __shared__ float H7[516];
  __shared__ float4 wpack[16];
  const int tid = threadIdx.x;
  const float* row = lo3 + (size_t)b * 8196;
  for (int j4 = tid; j4 < 2048; j4 += 512)
    *reinterpret_cast<float4*>(A + 4 * j4) =
        *reinterpret_cast<const float4*>(row + 4 * j4);
  if (tid == 0) A[8192] = row[8192];
  __syncthreads();
  fwd_tail_level(A, Bb, 8193, 4097, H4, tid);
  __syncthreads();
  fwd_tail_level(Bb, A, 4097, 2049, H5, tid);
  __syncthreads();
  fwd_tail_level(A, Bb, 2049, 1025, H6, tid);
  __syncthreads();
  fwd_tail_level(Bb, A, 1025, 513, H7, tid);
  inv_tail_level(A, Bb, 513, H7, filt, b, 7, tid, wpack);
  inv_tail_level(Bb, A, 1025, H6, filt, b, 6, tid, wpack);
  inv_tail_level(A, Bb, 2049, H5, filt, b, 5, tid, wpack);
  inv_tail_level(Bb, prev3out + (size_t)b * 8196, 4097, H4, filt, b, 4, tid,
                 wpack);
}

extern "C" void kernel_launch(void* const* d_in, const int* in_sizes, int n_in,
                              void* d_out, int out_size, void* d_ws,
                              size_t ws_size, hipStream_t stream) {
  const float* x = (const float*)d_in[0];
  const float* filt = (const float*)d_in[1];
  float* out = (float*)d_out;
  float* ws = (float*)d_ws;

  const int B = 128;
  float* lo3buf = ws;
  float* prev3buf = lo3buf + (size_t)B * 8196;
  float* hi0 = prev3buf + (size_t)B * 8196;
  float* hi1 = hi0 + (size_t)B * 65540;
  float* hi2 = hi1 + (size_t)B * 32772;
  float* hi3 = hi2 + (size_t)B * 16388;
  float* prev1buf = hi3 + (size_t)B * 8196;

  hipLaunchKernelGGL(fwd03, dim3(17, B), dim3(256), 0, stream, x, hi0, hi1,
                     hi2, hi3, lo3buf);
  hipLaunchKernelGGL(mid_fused, dim3(B), dim3(512), 0, stream, lo3buf, filt,
                     prev3buf);

  // inv levels 3+2 fused: prev3(8193)+hi3 -> [prev2 in regs] + hi2 -> prev1
  hipLaunchKernelGGL(inv_fused2, dim3(9, B), dim3(256), 0, stream, prev3buf,
                     hi3, hi2, filt, 3, 2, 8193, 8196, 16385, 16388, 32769,
                     32772, prev1buf);
  // inv levels 1+0 fused: prev1(32769)+hi1 -> [prev0 in regs] + hi0 -> out
  hipLaunchKernelGGL(inv_fused2, dim3(32, B), dim3(256), 0, stream, prev1buf,
                     hi1, hi0, filt, 1, 0, 32769, 32772, 65537, 65540, 131072,
                     131072, out);
}

// Round 12
// 134.449 us; speedup vs baseline: 1.1635x; 1.1635x over previous
//
#include <hip/hip_runtime.h>

// 8-level DWT + 8-level per-channel IDWT.
//  fwd03: wave-local barrier-free pyramid (r10); hi0..hi3 stored BF16.
//  mid_fused: fwd 4-7 + inv 7-4 per row; prev3 written BF16.
//  inverse levels 3..0: flat per-level kernels reading/writing BF16
//  intermediates (final level writes fp32 out).

static __constant__ float c_dec_lo[10] = {
    0.003335725285001549f, -0.012580751999015526f, -0.006241490213011705f,
    0.07757149384006515f, -0.03224486958502952f, -0.24229488706619015f,
    0.13842814590110342f, 0.7243085284385744f, 0.6038292697974729f,
    0.160102397974125f};
static __constant__ float c_dec_hi[10] = {
    -0.160102397974125f, 0.6038292697974729f, -0.7243085284385744f,
    0.13842814590110342f, 0.24229488706619015f, -0.03224486958502952f,
    -0.07757149384006515f, -0.006241490213011705f, 0.012580751999015526f,
    0.003335725285001549f};

// ---------------- bf16 helpers ----------------
__device__ inline unsigned int f2bf_bits(float f) {
  unsigned int u = __float_as_uint(f);
  u += 0x7FFFu + ((u >> 16) & 1u);  // RNE
  return u >> 16;
}
__device__ inline unsigned int pack2(float a, float b) {
  return f2bf_bits(a) | (f2bf_bits(b) << 16);
}
__device__ inline float bf2f(unsigned short s) {
  return __uint_as_float(((unsigned int)s) << 16);
}
__device__ inline void unpack8(uint4 t, float* v) {
  v[0] = __uint_as_float(t.x << 16); v[1] = __uint_as_float(t.x & 0xFFFF0000u);
  v[2] = __uint_as_float(t.y << 16); v[3] = __uint_as_float(t.y & 0xFFFF0000u);
  v[4] = __uint_as_float(t.z << 16); v[5] = __uint_as_float(t.z & 0xFFFF0000u);
  v[6] = __uint_as_float(t.w << 16); v[7] = __uint_as_float(t.w & 0xFFFF0000u);
}
// src 16B-aligned; 24 bf16 -> v[0..23]
__device__ inline void load24bf(const unsigned short* src, float* v) {
  const uint4* p = reinterpret_cast<const uint4*>(src);
  unpack8(p[0], v);
  unpack8(p[1], v + 8);
  unpack8(p[2], v + 16);
}
__device__ inline void store4bf(unsigned short* dst, const float* a) {
  *reinterpret_cast<uint2*>(dst) = make_uint2(pack2(a[0], a[1]), pack2(a[2], a[3]));
}
__device__ inline void store8bf(unsigned short* dst, const float* a) {
  *reinterpret_cast<uint4*>(dst) =
      make_uint4(pack2(a[0], a[1]), pack2(a[2], a[3]), pack2(a[4], a[5]),
                 pack2(a[6], a[7]));
}
__device__ inline void store16bf(unsigned short* dst, const float* a) {
  store8bf(dst, a);
  store8bf(dst + 8, a + 8);
}

// ---------------- fp32 helpers ----------------
__device__ inline float4 ldz4(const float* __restrict__ row, int j, int L) {
  if (j >= 0 && j + 3 < L) return *reinterpret_cast<const float4*>(row + j);
  float4 r;
  r.x = (j + 0 >= 0 && j + 0 < L) ? row[j + 0] : 0.f;
  r.y = (j + 1 >= 0 && j + 1 < L) ? row[j + 1] : 0.f;
  r.z = (j + 2 >= 0 && j + 2 < L) ? row[j + 2] : 0.f;
  r.w = (j + 3 >= 0 && j + 3 < L) ? row[j + 3] : 0.f;
  return r;
}

__device__ inline void load20(const float* src, int base, float* v) {
#pragma unroll
  for (int q = 0; q < 5; ++q) {
    const float4 t = *reinterpret_cast<const float4*>(src + base + 4 * q);
    v[4 * q + 0] = t.x; v[4 * q + 1] = t.y;
    v[4 * q + 2] = t.z; v[4 * q + 3] = t.w;
  }
}

__device__ inline void load20z(const float* __restrict__ src, int base, int L,
                               float* v) {
#pragma unroll
  for (int q = 0; q < 5; ++q) {
    const float4 t = ldz4(src, base + 4 * q, L);
    v[4 * q + 0] = t.x; v[4 * q + 1] = t.y;
    v[4 * q + 2] = t.z; v[4 * q + 3] = t.w;
  }
}

__device__ inline void load12(const float* src, float* v) {
#pragma unroll
  for (int q = 0; q < 3; ++q) {
    const float4 t = *reinterpret_cast<const float4*>(src + 4 * q);
    v[4 * q + 0] = t.x; v[4 * q + 1] = t.y;
    v[4 * q + 2] = t.z; v[4 * q + 3] = t.w;
  }
}

__device__ inline void fir10x2(const float* v, float* lo, float* hv) {
#pragma unroll
  for (int i = 0; i < 4; ++i) {
    float a = 0.f, h = 0.f;
#pragma unroll
    for (int k = 0; k < 10; ++k) {
      const float xx = v[2 * i + 3 + k];
      a += xx * c_dec_lo[k];
      h += xx * c_dec_hi[k];
    }
    lo[i] = a; hv[i] = h;
  }
}

__device__ inline void fir10x2_split(const float* e, const float* o,
                                     float* lo, float* hv) {
#pragma unroll
  for (int i = 0; i < 4; ++i) {
    float a = 0.f, h = 0.f;
#pragma unroll
    for (int m = 0; m < 5; ++m) {
      const float ov = o[i + 1 + m], ev = e[i + 2 + m];
      a += ov * c_dec_lo[2 * m] + ev * c_dec_lo[2 * m + 1];
      h += ov * c_dec_hi[2 * m] + ev * c_dec_hi[2 * m + 1];
    }
    lo[i] = a; hv[i] = h;
  }
}

__device__ inline void store_hi(float* hg, int A, int idx, const float* hv,
                                int es, int ee) {
  if (idx >= es && idx + 3 < ee) {
    *reinterpret_cast<float4*>(hg + A + idx) =
        make_float4(hv[0], hv[1], hv[2], hv[3]);
  } else {
#pragma unroll
    for (int i = 0; i < 4; ++i)
      if (idx + i >= es && idx + i < ee) hg[A + idx + i] = hv[i];
  }
}

__device__ inline void store_hi_bf(unsigned short* hg, int A, int idx,
                                   const float* hv, int es, int ee) {
  if (idx >= es && idx + 3 < ee) {
    store4bf(hg + A + idx, hv);
  } else {
#pragma unroll
    for (int i = 0; i < 4; ++i)
      if (idx + i >= es && idx + i < ee)
        hg[A + idx + i] = (unsigned short)f2bf_bits(hv[i]);
  }
}

__device__ inline void st4(float* dst, const float* a) {
  *reinterpret_cast<float4*>(dst) = make_float4(a[0], a[1], a[2], a[3]);
}

__device__ inline void store_pad_split(float* E, float* O, int idx,
                                       const float* lo, int vlo, int vhi) {
#pragma unroll
  for (int i = 0; i < 4; ++i) {
    const int s = idx + i;
    const float val = (s >= vlo && s < vhi) ? lo[i] : 0.f;
    if (s & 1) O[s >> 1] = val;
    else E[s >> 1] = val;
  }
}

__device__ inline void wave_sync() {
  __builtin_amdgcn_wave_barrier();
  asm volatile("s_waitcnt lgkmcnt(0)" ::: "memory");
  __builtin_amdgcn_wave_barrier();
}

// ---------------- fwd levels 0-3: wave-local pyramid, bf16 hi ---------------
template <bool FAST>
__device__ inline void wl_level0(const float* __restrict__ xr, float* E0,
                                 float* O0, unsigned short* __restrict__ h0,
                                 int A0, int xoff, int vlo, int vhi, int eeh,
                                 int lane) {
#pragma unroll
  for (int i = 0; i < 5; ++i) {
    const int idx = 4 * lane + 256 * i;
    if (idx < 1108) {
      float v[20];
      if (FAST) load20(xr, 2 * idx + xoff, v);
      else load20z(xr, 2 * idx + xoff, 131072, v);
      float lo[4], hv[4];
      fir10x2(v, lo, hv);
      if (FAST) {
        const int j = idx >> 1;
        *reinterpret_cast<float2*>(E0 + j) = make_float2(lo[0], lo[2]);
        *reinterpret_cast<float2*>(O0 + j) = make_float2(lo[1], lo[3]);
        if (idx >= 56 && idx < 1080) store4bf(h0 + A0 + idx, hv);
      } else {
        store_pad_split(E0, O0, idx, lo, vlo, vhi);
        store_hi_bf(h0, A0, idx, hv, 56, eeh);
      }
    }
  }
}

template <bool FAST>
__device__ inline void wl_levelN(const float* Ein, const float* Oin,
                                 float* Eout, float* Oout,
                                 unsigned short* __restrict__ hg, int A,
                                 int NOUT, int iters, int esHi, int eeHiF,
                                 int vlo, int vhi, int lane) {
  for (int i = 0; i < iters; ++i) {
    const int idx = 4 * lane + 256 * i;
    if (idx < NOUT) {
      float e[12], o[12];
      load12(Ein + idx, e);
      load12(Oin + idx, o);
      float lo[4], hv[4];
      fir10x2_split(e, o, lo, hv);
      if (FAST) {
        const int j = idx >> 1;
        *reinterpret_cast<float2*>(Eout + j) = make_float2(lo[0], lo[2]);
        *reinterpret_cast<float2*>(Oout + j) = make_float2(lo[1], lo[3]);
        if (idx >= esHi && idx < eeHiF) store4bf(hg + A + idx, hv);
      } else {
        store_pad_split(Eout, Oout, idx, lo, vlo, vhi);
        store_hi_bf(hg, A, idx, hv, esHi, min(eeHiF, vhi));
      }
    }
  }
}

template <bool FAST>
__device__ inline void wl_level3(const float* Ein, const float* Oin,
                                 float* __restrict__ l3,
                                 unsigned short* __restrict__ h3, int T,
                                 int ne3, int lane) {
  const int idx = 4 * lane;
  if (idx >= 128) return;
  float e[12], o[12];
  load12(Ein + idx, e);
  load12(Oin + idx, o);
  float lo[4], hv[4];
  fir10x2_split(e, o, lo, hv);
  if (FAST) {
    st4(l3 + T + idx, lo);
    store4bf(h3 + T + idx, hv);
  } else {
    store_hi(l3, T, idx, lo, 0, ne3);
    store_hi_bf(h3, T, idx, hv, 0, ne3);
  }
}

__global__ __launch_bounds__(256) void fwd03(
    const float* __restrict__ x, unsigned short* __restrict__ hi0,
    unsigned short* __restrict__ hi1, unsigned short* __restrict__ hi2,
    unsigned short* __restrict__ hi3, float* __restrict__ lo3) {
  const int b = blockIdx.y;
  const int widx = threadIdx.x >> 6;
  const int lane = threadIdx.x & 63;
  const int gw = blockIdx.x * 4 + widx;
  __shared__ float W[7744];
  float* E0 = W + widx * 1936;
  float* O0 = E0 + 556;
  float* E1 = O0 + 556;
  float* O1 = E1 + 276;
  float* E2 = O1 + 276;
  float* O2 = E2 + 136;
  if (gw > 64) return;
  const int T = gw * 128;
  const float* xr = x + (size_t)b * 131072;
  unsigned short* h0 = hi0 + (size_t)b * 65544;
  unsigned short* h1 = hi1 + (size_t)b * 32776;
  unsigned short* h2 = hi2 + (size_t)b * 16392;
  unsigned short* h3 = hi3 + (size_t)b * 8200;
  float* l3 = lo3 + (size_t)b * 8196;
  const int A0 = 8 * T - 56, A1 = 4 * T - 24, A2 = 2 * T - 8;
  const int xoff = 16 * T - 120;

  if (gw >= 1 && gw <= 62) {
    wl_level0<true>(xr, E0, O0, h0, A0, xoff, 0, 0, 0, lane);
    wave_sync();
    wl_levelN<true>(E0, O0, E1, O1, h1, A1, 548, 3, 24, 536, 0, 0, lane);
    wave_sync();
    wl_levelN<true>(E1, O1, E2, O2, h2, A2, 268, 2, 8, 264, 0, 0, lane);
    wave_sync();
    wl_level3<true>(E2, O2, l3, h3, T, 128, lane);
  } else {
    wl_level0<false>(xr, E0, O0, h0, A0, xoff, (A0 < 0) ? -A0 : 0,
                     min(1108, 65537 - A0), min(1080, 65537 - A0), lane);
    wave_sync();
    wl_levelN<false>(E0, O0, E1, O1, h1, A1, 548, 3, 24, 536,
                     (A1 < 0) ? -A1 : 0, min(548, 32769 - A1), lane);
    wave_sync();
    wl_levelN<false>(E1, O1, E2, O2, h2, A2, 268, 2, 8, 264,
                     (A2 < 0) ? -A2 : 0, min(268, 16385 - A2), lane);
    wave_sync();
    wl_level3<false>(E2, O2, l3, h3, T, min(128, 8193 - T), lane);
  }
}

// ---------------- inverse accumulator ----------------
template <int NE>
__device__ inline void accum_pairs(const float* p, const float* h,
                                   const float4* wpk, float* acc) {
#pragma unroll
  for (int i = 0; i < 2 * NE; ++i) acc[i] = 0.f;
#pragma unroll
  for (int m = 0; m < 16; ++m) {
    const float4 w = wpk[m];
#pragma unroll
    for (int e = 0; e < NE; ++e) {
      const float pv = p[e + 1 + m], hv = h[e + 1 + m];
      acc[2 * e + 0] += pv * w.y + hv * w.w;
      acc[2 * e + 1] += pv * w.x + hv * w.z;
    }
  }
}

__device__ inline void inv_accum(const float* p, const float* h,
                                 const float4* wpk, float* acc) {
  accum_pairs<4>(p, h, wpk, acc);
}

// ---------------- flat inverse level, bf16 in / bf16-or-fp32 out ------------
template <bool OUTF32>
__global__ __launch_bounds__(256) void inv_big_bf(
    const unsigned short* __restrict__ prev,
    const unsigned short* __restrict__ hicoef, const float* __restrict__ filt,
    int level, int L, int sIn, int Tout, int sOut, float* __restrict__ outf,
    unsigned short* __restrict__ outb) {
  const int c = blockIdx.y;
  __shared__ float4 wpack[16];
  const int tid = threadIdx.x;
  if (tid < 16) {
    const float* f = filt + ((size_t)c * 8 + level) * 64;
    wpack[tid] = make_float4(f[2 * tid], f[2 * tid + 1], f[32 + 2 * tid],
                             f[32 + 2 * tid + 1]);
  }
  __syncthreads();
  const int g = blockIdx.x * 256 + tid;
  const int t0 = 16 * g;
  if (t0 >= Tout) return;
  const int U = 8 * g - 8;
  const unsigned short* prow = prev + (size_t)c * sIn;
  const unsigned short* hrow = hicoef + (size_t)c * sIn;
  float p[24], h[24];
  const bool interior = (U >= 0) && (U + 23 < L) && (t0 + 15 < Tout);
  if (interior) {
    load24bf(prow + U, p);
    load24bf(hrow + U, h);
  } else {
#pragma unroll
    for (int q = 0; q < 24; ++q) {
      const int j = U + q;
      p[q] = (j >= 0 && j < L) ? bf2f(prow[j]) : 0.f;
      h[q] = (j >= 0 && j < L) ? bf2f(hrow[j]) : 0.f;
    }
  }
  float acc[16];
  accum_pairs<8>(p, h, wpack, acc);
  if (OUTF32) {
    float* orow = outf + (size_t)c * sOut;
    if (interior) {
#pragma unroll
      for (int q = 0; q < 4; ++q)
        *reinterpret_cast<float4*>(orow + t0 + 4 * q) =
            make_float4(acc[4 * q], acc[4 * q + 1], acc[4 * q + 2],
                        acc[4 * q + 3]);
    } else {
#pragma unroll
      for (int i = 0; i < 16; ++i)
        if (t0 + i < Tout) orow[t0 + i] = acc[i];
    }
  } else {
    unsigned short* orow = outb + (size_t)c * sOut;
    if (interior) {
      store16bf(orow + t0, acc);
    } else {
#pragma unroll
      for (int i = 0; i < 16; ++i)
        if (t0 + i < Tout) orow[t0 + i] = (unsigned short)f2bf_bits(acc[i]);
    }
  }
}

// ---------------- middle: fwd 4-7 + inv 7-4, one block per row --------------
__device__ inline void fwd_tail_level(const float* __restrict__ in,
                                      float* __restrict__ outp, int L, int D,
                                      float* __restrict__ hirow, int tid) {
  for (int d0 = 4 * tid; d0 < D; d0 += 2048) {
    const int jb = 2 * d0 - 8;
    float v[20];
    const bool interior = (jb >= 0) && (jb + 19 < L) && (d0 + 3 < D);
    if (interior) {
      load20(in, jb, v);
    } else {
#pragma unroll
      for (int q = 0; q < 20; ++q) {
        const int j = jb + q;
        v[q] = (j >= 0 && j < L) ? in[j] : 0.f;
      }
    }
    float lo[4], hv[4];
    fir10x2(v, lo, hv);
    if (interior) {
      st4(outp + d0, lo);
      st4(hirow + d0, hv);
    } else {
#pragma unroll
      for (int i = 0; i < 4; ++i)
        if (d0 + i < D) { outp[d0 + i] = lo[i]; hirow[d0 + i] = hv[i]; }
    }
  }
}

__device__ inline void inv_tail_level(const float* __restrict__ pin,
                                      float* __restrict__ pout, int L,
                                      const float* __restrict__ hirow,
                                      const float* __restrict__ filt, int c,
                                      int level, int tid, float4* wpack) {
  __syncthreads();
  if (tid < 16) {
    const float* f = filt + ((size_t)c * 8 + level) * 64;
    wpack[tid] = make_float4(f[2 * tid], f[2 * tid + 1], f[32 + 2 * tid],
                             f[32 + 2 * tid + 1]);
  }
  __syncthreads();
  const int Tout = 2 * L - 1;
  for (int t0 = 8 * tid; t0 < Tout; t0 += 4096) {
    const int U = t0 / 2 - 8;
    float p[20], h[20];
    if (U >= 0 && U + 19 < L) {
      load20(pin, U, p);
      load20(hirow, U, h);
    } else {
#pragma unroll
      for (int q = 0; q < 20; ++q) {
        const int j = U + q;
        p[q] = (j >= 0 && j < L) ? pin[j] : 0.f;
        h[q] = (j >= 0 && j < L) ? hirow[j] : 0.f;
      }
    }
    float acc[8];
    inv_accum(p, h, wpack, acc);
    if (t0 + 7 < Tout) {
      st4(pout + t0, acc);
      st4(pout + t0 + 4, acc + 4);
    } else {
#pragma unroll
      for (int i = 0; i < 8; ++i)
        if (t0 + i < Tout) pout[t0 + i] = acc[i];
    }
  }
}

// Final mid stage: write prev3 to global as bf16.
__device__ inline void inv_tail_level_gbf(const float* __restrict__ pin,
                                          unsigned short* __restrict__ poutg,
                                          int L,
                                          const float* __restrict__ hirow,
                                          const float* __restrict__ filt,
                                          int c, int level, int tid,
                                          float4* wpack) {
  __syncthreads();
  if (tid < 16) {
    const float* f = filt + ((size_t)c * 8 + level) * 64;
    wpack[tid] = make_float4(f[2 * tid], f[2 * tid + 1], f[32 + 2 * tid],
                             f[32 + 2 * tid + 1]);
  }
  __syncthreads();
  const int Tout = 2 * L - 1;
  for (int t0 = 8 * tid; t0 < Tout; t0 += 4096) {
    const int U = t0 / 2 - 8;
    float p[20], h[20];
    if (U >= 0 && U + 19 < L) {
      load20(pin, U, p);
      load20(hirow, U, h);
    } else {
#pragma unroll
      for (int q = 0; q < 20; ++q) {
        const int j = U + q;
        p[q] = (j >= 0 && j < L) ? pin[j] : 0.f;
        h[q] = (j >= 0 && j < L) ? hirow[j] : 0.f;
      }
    }
    float acc[8];
    inv_accum(p, h, wpack, acc);
    if (t0 + 7 < Tout) {
      store8bf(poutg + t0, acc);
    } else {
#pragma unroll
      for (int i = 0; i < 8; ++i)
        if (t0 + i < Tout) poutg[t0 + i] = (unsigned short)f2bf_bits(acc[i]);
    }
  }
}

__global__ __launch_bounds__(512) void mid_fused(
    const float* __restrict__ lo3, const float* __restrict__ filt,
    unsigned short* __restrict__ prev3out) {
  const int b = blockIdx.x;
  __shared__ float A[8200];
  __shared__ float Bb[4104];
  __shared__ float H4[4100];
  __shared__ float H5[2052];
  __shared__ float H6[1028];
  __shared__ float H7[516];
  __shared__ float4 wpack[16];
  const int tid = threadIdx.x;
  const float* row = lo3 + (size_t)b * 8196;
  for (int j4 = tid; j4 < 2048; j4 += 512)
    *reinterpret_cast<float4*>(A + 4 * j4) =
        *reinterpret_cast<const float4*>(row + 4 * j4);
  if (tid == 0) A[8192] = row[8192];
  __syncthreads();
  fwd_tail_level(A, Bb, 8193, 4097, H4, tid);
  __syncthreads();
  fwd_tail_level(Bb, A, 4097, 2049, H5, tid);
  __syncthreads();
  fwd_tail_level(A, Bb, 2049, 1025, H6, tid);
  __syncthreads();
  fwd_tail_level(Bb, A, 1025, 513, H7, tid);
  inv_tail_level(A, Bb, 513, H7, filt, b, 7, tid, wpack);
  inv_tail_level(Bb, A, 1025, H6, filt, b, 6, tid, wpack);
  inv_tail_level(A, Bb, 2049, H5, filt, b, 5, tid, wpack);
  inv_tail_level_gbf(Bb, prev3out + (size_t)b * 8200, 4097, H4, filt, b, 4,
                     tid, wpack);
}

extern "C" void kernel_launch(void* const* d_in, const int* in_sizes, int n_in,
                              void* d_out, int out_size, void* d_ws,
                              size_t ws_size, hipStream_t stream) {
  const float* x = (const float*)d_in[0];
  const float* filt = (const float*)d_in[1];
  float* out = (float*)d_out;

  const int B = 128;
  // Workspace layout (bf16 intermediates; every base 16B-aligned).
  char* base = (char*)d_ws;
  float* lo3buf = (float*)base;                       // 128 x 8196 f32
  base += (size_t)B * 8196 * 4;
  unsigned short* prev3 = (unsigned short*)base;      // 128 x 8200 bf16
  base += (size_t)B * 8200 * 2;
  unsigned short* hi0 = (unsigned short*)base;        // 128 x 65544
  base += (size_t)B * 65544 * 2;
  unsigned short* hi1 = (unsigned short*)base;        // 128 x 32776
  base += (size_t)B * 32776 * 2;
  unsigned short* hi2 = (unsigned short*)base;        // 128 x 16392
  base += (size_t)B * 16392 * 2;
  unsigned short* hi3 = (unsigned short*)base;        // 128 x 8200
  base += (size_t)B * 8200 * 2;
  unsigned short* prev2 = (unsigned short*)base;      // 128 x 16392
  base += (size_t)B * 16392 * 2;
  unsigned short* prev1 = (unsigned short*)base;      // 128 x 32776
  base += (size_t)B * 32776 * 2;
  unsigned short* prev0 = (unsigned short*)base;      // 128 x 65544

  hipLaunchKernelGGL(fwd03, dim3(17, B), dim3(256), 0, stream, x, hi0, hi1,
                     hi2, hi3, lo3buf);
  hipLaunchKernelGGL(mid_fused, dim3(B), dim3(512), 0, stream, lo3buf, filt,
                     prev3);

  auto ginv = [](int Tout) {
    const int tpr = (Tout + 15) / 16;
    return (tpr + 255) / 256;
  };
  hipLaunchKernelGGL((inv_big_bf<false>), dim3(ginv(16385), B), dim3(256), 0,
                     stream, prev3, hi3, filt, 3, 8193, 8200, 16385, 16392,
                     (float*)nullptr, prev2);
  hipLaunchKernelGGL((inv_big_bf<false>), dim3(ginv(32769), B), dim3(256), 0,
                     stream, prev2, hi2, filt, 2, 16385, 16392, 32769, 32776,
                     (float*)nullptr, prev1);
  hipLaunchKernelGGL((inv_big_bf<false>), dim3(ginv(65537), B), dim3(256), 0,
                     stream, prev1, hi1, filt, 1, 32769, 32776, 65537, 65544,
                     (float*)nullptr, prev0);
  hipLaunchKernelGGL((inv_big_bf<true>), dim3(ginv(131072), B), dim3(256), 0,
                     stream, prev0, hi0, filt, 0, 65537, 65544, 131072, 131072,
                     out, (unsigned short*)nullptr);
}